// Round 5
// baseline (84.376 us; speedup 1.0000x reference)
//
#include <hip/hip_runtime.h>

#define N_KPS 1024
#define N_PTS 120000
#define BLOCK 256                 // 4 waves per block
#define KSPLIT 4                  // one wave per K-chunk
#define NGROUPS (N_KPS / 2)       // 512 ctrl-point pairs
#define GPW (NGROUPS / KSPLIT)    // 128 groups per wave

typedef float v2f __attribute__((ext_vector_type(2)));

// Setup: interleave control data pairwise-SoA into ws so the main loop can use
// uniform 64-bit loads as VOP3P SGPR-pair operands (no per-iteration broadcast
// movs — r4's hidden cost). Layout (float2 units):
//   ws[0..512)      : {kx_i, kx_{i+1}}
//   ws[512..1024)   : {ky_i, ky_{i+1}}
//   ws[1024..1536)  : {wx_i, wx_{i+1}}
//   ws[1536..2048)  : {wy_i, wy_{i+1}}
__global__ __launch_bounds__(512) void tps_setup_kernel(
    const float* __restrict__ kps,
    const float* __restrict__ W,
    float2*      __restrict__ ws)
{
    const int t = threadIdx.x;            // 0..511, one ctrl-pair each
    float2 kx = make_float2(kps[4 * t],     kps[4 * t + 2]);
    float2 ky = make_float2(kps[4 * t + 1], kps[4 * t + 3]);
    float2 wx = make_float2(W[4 * t],       W[4 * t + 2]);
    float2 wy = make_float2(W[4 * t + 1],   W[4 * t + 3]);
    ws[t]             = kx;
    ws[512 + t]       = ky;
    ws[1024 + t]      = wx;
    ws[1536 + t]      = wy;
}

// Main: one thread per query point (64 points/block), split-K x4 across the
// block's 4 waves. Packed axis = control points: each v_pk op processes 2 ctrl
// points; query-point broadcasts {p.x,p.x} are loop-invariant VGPR pairs.
// Inner loop per 2 ctrl: pk_sub, pk_sub, pk_mul, pk_fma, pk_max, 2x v_log_f32,
// pk_mul, pk_fma, pk_fma = 8 pk (16 cyc) + 2 trans (~16 cyc) per 128 pairs.
__global__ __launch_bounds__(BLOCK) void tps_warp_kernel(
    const float2* __restrict__ pts,
    const float*  __restrict__ W,
    const float2* __restrict__ ws,
    float2*       __restrict__ out)
{
    __shared__ float2 part[KSPLIT][64];

    const int lane = threadIdx.x & 63;
    // Provably wave-uniform wave id -> SGPR -> scalar loads for control data.
    const int wv = __builtin_amdgcn_readfirstlane(threadIdx.x) >> 6;

    const int j = blockIdx.x * 64 + lane;     // 1875*64 == 120000, exact cover
    const float2 p = pts[j];

    const v2f px = {p.x, p.x};                // loop-invariant broadcasts
    const v2f py = {p.y, p.y};
    const v2f tiny = {1e-37f, 1e-37f};
    v2f zx = {0.0f, 0.0f};
    v2f zy = {0.0f, 0.0f};

    const float2* __restrict__ KX = ws;
    const float2* __restrict__ KY = ws + 512;
    const float2* __restrict__ WX = ws + 1024;
    const float2* __restrict__ WY = ws + 1536;

    const int g0 = wv * GPW;
    #pragma unroll 8
    for (int g = g0; g < g0 + GPW; ++g) {
        // Uniform index -> s_load_dwordx2 (merged across unroll); the loaded
        // SGPR pair feeds VOP3P directly as its one scalar operand.
        float2 kx = KX[g];
        float2 ky = KY[g];
        float2 wx = WX[g];
        float2 wy = WY[g];

        v2f dx = v2f{kx.x, kx.y} - px;                        // v_pk_add (neg)
        v2f dy = v2f{ky.x, ky.y} - py;
        v2f d2 = __builtin_elementwise_fma(dy, dy, dx * dx);  // pk_mul + pk_fma
        // d2==0 -> clamp: v = 1e-37*log2(1e-37) ~ 0, matching reference's
        // where(l2==0, 1.0) -> 0.5*1*ln(1) = 0.
        d2 = __builtin_elementwise_max(d2, tiny);             // v_pk_max_f32
        v2f t;
        t.x = __log2f(d2.x);                                  // v_log_f32
        t.y = __log2f(d2.y);
        v2f v = d2 * t;                                       // pk_mul
        zx = __builtin_elementwise_fma(v, v2f{wx.x, wx.y}, zx);
        zy = __builtin_elementwise_fma(v, v2f{wy.x, wy.y}, zy);
    }

    part[wv][lane] = make_float2(zx.x + zx.y, zy.x + zy.y);
    __syncthreads();

    if (wv == 0) {
        float2 a = part[0][lane];
        float2 b = part[1][lane];
        float2 c = part[2][lane];
        float2 d = part[3][lane];
        float sx = (a.x + b.x) + (c.x + d.x);
        float sy = (a.y + b.y) + (c.y + d.y);

        const float scale = 0.34657359027997264f;  // 0.5 * ln(2)
        float w1x = W[2048], w1y = W[2049];
        float wxx = W[2050], wxy = W[2051];
        float wyx = W[2052], wyy = W[2053];

        float ox = p.x + fmaf(scale, sx, fmaf(wxx, p.x, fmaf(wyx, p.y, w1x)));
        float oy = p.y + fmaf(scale, sy, fmaf(wxy, p.x, fmaf(wyy, p.y, w1y)));
        out[j] = make_float2(ox, oy);
    }
}

extern "C" void kernel_launch(void* const* d_in, const int* in_sizes, int n_in,
                              void* d_out, int out_size, void* d_ws, size_t ws_size,
                              hipStream_t stream) {
    const float* pts = (const float*)d_in[0];   // [120000, 2]
    const float* kps = (const float*)d_in[1];   // [1024, 2]
    const float* W   = (const float*)d_in[2];   // [1027, 2]
    float* out = (float*)d_out;                 // [120000, 2]
    float2* ws = (float2*)d_ws;                 // 16 KB interleaved ctrl data

    tps_setup_kernel<<<1, 512, 0, stream>>>(kps, W, ws);

    const int grid = N_PTS / 64;                // 1875, exact
    tps_warp_kernel<<<grid, BLOCK, 0, stream>>>(
        (const float2*)pts, W, (const float2*)ws, (float2*)out);
}